// Round 2
// 293.048 us; speedup vs baseline: 1.0215x; 1.0215x over previous
//
#include <hip/hip_runtime.h>

// LengthRegulator: B=32, T_src=1024, H=512 fixed by the problem.
// d_out layout: [expanded (B*max_len*H) f32][mel_masks (B*max_len) f32(0/1)]
// max_len recovered from out_size = B*max_len*(H+1).
//
// R5b: source-row-major copy (R5 + nontemporal-store type fix).
//   A) lr_prep: per-batch inclusive scan of durations -> cum[] in workspace,
//      plus mask write. No idx scatter buffer anymore.
//   B) lr_copy: ONE WAVE PER SOURCE FRAME (b,s). Loads the 2 KB x-row once
//      (address independent of cum -> load issues immediately, no dependent
//      gather chain), then stores it dur[b][s] times into
//      out[cum[s-1]..cum[s]). Pad rows [total, max_len) are zero-filled by
//      the same kernel (all 256 CUs, not prep's 32). Nontemporal stores:
//      out is write-once, keep x in L2/L3.
//   Mandatory traffic: 246 MB writes + 64 MB reads ≈ 50 µs @ 6.3 TB/s.

#define B_SZ   32
#define T_SRC  1024
#define H_DIM  512

// clang native vector type: __builtin_nontemporal_store requires a pointer to
// a scalar or true vector type, not HIP's float4 struct.
typedef float f4 __attribute__((ext_vector_type(4)));

__global__ void __launch_bounds__(T_SRC) lr_prep(const int* __restrict__ dur,
                                                 int* __restrict__ cum,
                                                 float* __restrict__ mask,
                                                 int max_len) {
    __shared__ int s[T_SRC];
    const int b   = blockIdx.x;
    const int tid = threadIdx.x;
    s[tid] = dur[b * T_SRC + tid];
    __syncthreads();
#pragma unroll
    for (int off = 1; off < T_SRC; off <<= 1) {
        int v = (tid >= off) ? s[tid - off] : 0;
        __syncthreads();
        s[tid] += v;
        __syncthreads();
    }
    cum[b * T_SRC + tid] = s[tid];
    const int total = s[T_SRC - 1];
    float* mb = mask + (size_t)b * max_len;
    for (int t = tid; t < max_len; t += T_SRC) mb[t] = (t < total) ? 0.0f : 1.0f;
}

// grid = (T_SRC/4, B), 256 threads = 4 waves/block. Wave index == source row s.
// Each lane carries 2 float4s (32 B) of the 2 KB row.
__global__ void __launch_bounds__(256) lr_copy(const float* __restrict__ x,
                                               const int* __restrict__ cum,
                                               float* __restrict__ out,
                                               int max_len) {
    const int b    = blockIdx.y;
    const int lane = threadIdx.x & 63;
    const int s    = (blockIdx.x << 2) | (threadIdx.x >> 6);

    const int* cb = cum + b * T_SRC;

    // x-row load: address is a pure function of (b,s) -> issues immediately,
    // overlaps the cum loads below.
    const f4* src = (const f4*)(x + ((size_t)b * T_SRC + s) * H_DIM);
    const f4 v0 = src[lane];
    const f4 v1 = src[lane + 64];

    const int end   = cb[s];
    const int start = s ? cb[s - 1] : 0;

    float* ob = out + (size_t)b * max_len * H_DIM;
    for (int t = start; t < end; ++t) {
        f4* dst = (f4*)(ob + (size_t)t * H_DIM);
        __builtin_nontemporal_store(v0, dst + lane);
        __builtin_nontemporal_store(v1, dst + lane + 64);
    }

    // Zero the padded tail, strided across this batch's T_SRC waves.
    const int total = cb[T_SRC - 1];
    const f4 z = (f4)(0.0f);
    for (int t = total + s; t < max_len; t += T_SRC) {
        f4* dst = (f4*)(ob + (size_t)t * H_DIM);
        __builtin_nontemporal_store(z, dst + lane);
        __builtin_nontemporal_store(z, dst + lane + 64);
    }
}

extern "C" void kernel_launch(void* const* d_in, const int* in_sizes, int n_in,
                              void* d_out, int out_size, void* d_ws, size_t ws_size,
                              hipStream_t stream) {
    const float* x   = (const float*)d_in[0];
    const int*   dur = (const int*)d_in[1];
    float*       out = (float*)d_out;
    int*         cumbuf = (int*)d_ws;   // B_SZ * T_SRC ints (128 KB)

    const int max_len = out_size / (B_SZ * (H_DIM + 1));
    float* mask = out + (size_t)B_SZ * max_len * H_DIM;

    lr_prep<<<B_SZ, T_SRC, 0, stream>>>(dur, cumbuf, mask, max_len);

    dim3 grid(T_SRC / 4, B_SZ);   // one wave per source frame
    lr_copy<<<grid, 256, 0, stream>>>(x, cumbuf, out, max_len);
}